// Round 8
// baseline (3795.305 us; speedup 1.0000x reference)
//
#include <hip/hip_runtime.h>

typedef unsigned int uint32;
typedef __attribute__((ext_vector_type(4))) float  f32x4;
typedef __attribute__((ext_vector_type(8))) short  bf16x8;
typedef __attribute__((ext_vector_type(4))) unsigned short us4;
typedef __attribute__((ext_vector_type(8))) unsigned short us8;

#define N_ROWS   16384
#define D_IN     512
#define D_DICT   8192
#define TOPK     256
#define BAND     2e-3f
#define BCAP     64
#define CCAP     1024

__device__ __forceinline__ unsigned short f2bf_rne(float f) {
    unsigned u = __float_as_uint(f);
    unsigned r = u + 0x7FFFu + ((u >> 16) & 1u);
    return (unsigned short)(r >> 16);
}
__device__ __forceinline__ float bf2f(unsigned short h) {
    return __uint_as_float(((unsigned)h) << 16);
}
__device__ __forceinline__ uint32 okey(float v) {
    uint32 u = __float_as_uint(v);
    return (u & 0x80000000u) ? ~u : (u | 0x80000000u);
}
// XOR-swizzled LDS element address for [256][64] bf16 tiles (validated r5-r7)
__device__ __forceinline__ int swz(int row, int k) {
    return row * 64 + (k ^ ((row & 7) << 3));
}

// ---------------------------------------------------------------------------
// Kernel 0: cast W_dec [512][8192] fp32 -> bf16 (same layout) into ws
// ---------------------------------------------------------------------------
__launch_bounds__(256)
__global__ void cast_wdec_kernel(const float* __restrict__ W,
                                 unsigned short* __restrict__ Wb) {
    size_t i = ((size_t)blockIdx.x * 256 + threadIdx.x) * 4;
    float4 v = *(const float4*)&W[i];
    us4 o;
    o.x = f2bf_rne(v.x); o.y = f2bf_rne(v.y);
    o.z = f2bf_rne(v.z); o.w = f2bf_rne(v.w);
    *(us4*)&Wb[i] = o;
}

// ---------------------------------------------------------------------------
// Kernel 1: MFMA encode via 3-term bf16 split (validated rounds 6-7).
// ---------------------------------------------------------------------------
__launch_bounds__(512)
__global__ void encode_mfma_kernel(const float* __restrict__ x,
                                   const float* __restrict__ Wenc,
                                   const float* __restrict__ b_enc,
                                   float* __restrict__ P,   // chunk-local
                                   int row0) {
    __shared__ unsigned short At[256 * 64];
    __shared__ unsigned short Bt[256 * 64];

    int tid  = threadIdx.x;
    int lane = tid & 63;
    int wid  = tid >> 6;
    int wm   = wid >> 2;
    int wn   = wid & 3;
    int bm   = blockIdx.x * 256;
    int bn   = blockIdx.y * 256;
    int fr   = lane & 15;
    int fk   = (lane >> 4) << 3;

    f32x4 acc[8][4];
    #pragma unroll
    for (int i = 0; i < 8; ++i)
        #pragma unroll
        for (int j = 0; j < 4; ++j) acc[i][j] = (f32x4)0.f;

    int srow = tid >> 1;
    int skb  = (tid & 1) << 4;

    for (int k0 = 0; k0 < D_IN; k0 += 32) {
        {
            const float* ax = x + (size_t)(row0 + bm + srow) * D_IN + k0 + skb;
            float4 a0 = ((const float4*)ax)[0];
            float4 a1 = ((const float4*)ax)[1];
            float4 a2 = ((const float4*)ax)[2];
            float4 a3 = ((const float4*)ax)[3];
            float av[16] = {a0.x,a0.y,a0.z,a0.w, a1.x,a1.y,a1.z,a1.w,
                            a2.x,a2.y,a2.z,a2.w, a3.x,a3.y,a3.z,a3.w};
            us8 h0, h1, l0, l1;
            #pragma unroll
            for (int j = 0; j < 8; ++j) {
                unsigned short hh = f2bf_rne(av[j]);
                h0[j] = hh; l0[j] = f2bf_rne(av[j] - bf2f(hh));
            }
            #pragma unroll
            for (int j = 0; j < 8; ++j) {
                unsigned short hh = f2bf_rne(av[8 + j]);
                h1[j] = hh; l1[j] = f2bf_rne(av[8 + j] - bf2f(hh));
            }
            *(us8*)&At[swz(srow, skb)]          = h0;
            *(us8*)&At[swz(srow, skb + 8)]      = h1;
            *(us8*)&At[swz(srow, 32 + skb)]     = l0;
            *(us8*)&At[swz(srow, 32 + skb + 8)] = l1;
        }
        {
            const float* bx = Wenc + (size_t)(bn + srow) * D_IN + k0 + skb;
            float4 b0 = ((const float4*)bx)[0];
            float4 b1 = ((const float4*)bx)[1];
            float4 b2 = ((const float4*)bx)[2];
            float4 b3 = ((const float4*)bx)[3];
            float bv[16] = {b0.x,b0.y,b0.z,b0.w, b1.x,b1.y,b1.z,b1.w,
                            b2.x,b2.y,b2.z,b2.w, b3.x,b3.y,b3.z,b3.w};
            us8 h0, h1, l0, l1;
            #pragma unroll
            for (int j = 0; j < 8; ++j) {
                unsigned short hh = f2bf_rne(bv[j]);
                h0[j] = hh; l0[j] = f2bf_rne(bv[j] - bf2f(hh));
            }
            #pragma unroll
            for (int j = 0; j < 8; ++j) {
                unsigned short hh = f2bf_rne(bv[8 + j]);
                h1[j] = hh; l1[j] = f2bf_rne(bv[8 + j] - bf2f(hh));
            }
            *(us8*)&Bt[swz(srow, skb)]          = h0;
            *(us8*)&Bt[swz(srow, skb + 8)]      = h1;
            *(us8*)&Bt[swz(srow, 32 + skb)]     = l0;
            *(us8*)&Bt[swz(srow, 32 + skb + 8)] = l1;
        }
        __syncthreads();

        bf16x8 bh[4], bl[4];
        #pragma unroll
        for (int nj = 0; nj < 4; ++nj) {
            bh[nj] = *(const bf16x8*)&Bt[swz(wn * 64 + nj * 16 + fr, fk)];
            bl[nj] = *(const bf16x8*)&Bt[swz(wn * 64 + nj * 16 + fr, 32 + fk)];
        }
        #pragma unroll
        for (int mi = 0; mi < 8; ++mi) {
            bf16x8 ah = *(const bf16x8*)&At[swz(wm * 128 + mi * 16 + fr, fk)];
            bf16x8 al = *(const bf16x8*)&At[swz(wm * 128 + mi * 16 + fr, 32 + fk)];
            #pragma unroll
            for (int nj = 0; nj < 4; ++nj) {
                acc[mi][nj] = __builtin_amdgcn_mfma_f32_16x16x32_bf16(ah, bh[nj], acc[mi][nj], 0, 0, 0);
                acc[mi][nj] = __builtin_amdgcn_mfma_f32_16x16x32_bf16(ah, bl[nj], acc[mi][nj], 0, 0, 0);
                acc[mi][nj] = __builtin_amdgcn_mfma_f32_16x16x32_bf16(al, bh[nj], acc[mi][nj], 0, 0, 0);
            }
        }
        __syncthreads();
    }

    #pragma unroll
    for (int mi = 0; mi < 8; ++mi) {
        int r0 = bm + wm * 128 + mi * 16 + (lane >> 4) * 4;
        #pragma unroll
        for (int nj = 0; nj < 4; ++nj) {
            int col = bn + wn * 64 + nj * 16 + fr;
            float bd = b_enc[col];
            #pragma unroll
            for (int reg = 0; reg < 4; ++reg)
                P[(size_t)(r0 + reg) * D_DICT + col] = acc[mi][nj][reg] + bd;
        }
    }
}

// ---------------------------------------------------------------------------
// Kernel 1b (fallback): exact fp32 encode GEMM (np rounding class).
// ---------------------------------------------------------------------------
#define EBK 8
#define ESTR 132

__launch_bounds__(256)
__global__ void encode_gemm_kernel(const float* __restrict__ X,
                                   const float* __restrict__ Wenc,
                                   const float* __restrict__ b_enc,
                                   float* __restrict__ P,
                                   int row0, int nrows) {
    __shared__ float As[EBK][ESTR];
    __shared__ float Bs[EBK][ESTR];
    int tid = threadIdx.x;
    int tx = tid & 15;
    int ty = tid >> 4;
    int bm = blockIdx.x * 128;
    int bn = blockIdx.y * 128;
    int srow = tid >> 1;
    int skq  = (tid & 1) * 4;

    float acc[8][8];
    #pragma unroll
    for (int i = 0; i < 8; ++i)
        #pragma unroll
        for (int j = 0; j < 8; ++j) acc[i][j] = 0.f;

    for (int k0 = 0; k0 < D_IN; k0 += EBK) {
        float4 a4 = make_float4(0.f, 0.f, 0.f, 0.f);
        if (bm + srow < nrows)
            a4 = *(const float4*)&X[(size_t)(row0 + bm + srow) * D_IN + k0 + skq];
        float4 b4 = *(const float4*)&Wenc[(size_t)(bn + srow) * D_IN + k0 + skq];
        As[skq + 0][srow] = a4.x; As[skq + 1][srow] = a4.y;
        As[skq + 2][srow] = a4.z; As[skq + 3][srow] = a4.w;
        Bs[skq + 0][srow] = b4.x; Bs[skq + 1][srow] = b4.y;
        Bs[skq + 2][srow] = b4.z; Bs[skq + 3][srow] = b4.w;
        __syncthreads();
        #pragma unroll
        for (int k = 0; k < EBK; ++k) {
            float4 a0 = *(const float4*)&As[k][ty * 4];
            float4 a1 = *(const float4*)&As[k][64 + ty * 4];
            float4 b0 = *(const float4*)&Bs[k][tx * 4];
            float4 b1 = *(const float4*)&Bs[k][64 + tx * 4];
            float a[8] = {a0.x, a0.y, a0.z, a0.w, a1.x, a1.y, a1.z, a1.w};
            float b[8] = {b0.x, b0.y, b0.z, b0.w, b1.x, b1.y, b1.z, b1.w};
            #pragma unroll
            for (int i = 0; i < 8; ++i)
                #pragma unroll
                for (int j = 0; j < 8; ++j)
                    acc[i][j] = fmaf(a[i], b[j], acc[i][j]);
        }
        __syncthreads();
    }

    float4 bias0 = *(const float4*)&b_enc[bn + tx * 4];
    float4 bias1 = *(const float4*)&b_enc[bn + 64 + tx * 4];
    float bb[8] = {bias0.x, bias0.y, bias0.z, bias0.w,
                   bias1.x, bias1.y, bias1.z, bias1.w};
    #pragma unroll
    for (int i = 0; i < 8; ++i) {
        int r = bm + (i < 4 ? ty * 4 + i : 64 + ty * 4 + (i - 4));
        if (r < nrows) {
            float4 o0, o1;
            o0.x = acc[i][0] + bb[0]; o0.y = acc[i][1] + bb[1];
            o0.z = acc[i][2] + bb[2]; o0.w = acc[i][3] + bb[3];
            o1.x = acc[i][4] + bb[4]; o1.y = acc[i][5] + bb[5];
            o1.z = acc[i][6] + bb[6]; o1.w = acc[i][7] + bb[7];
            *(float4*)&P[(size_t)r * D_DICT + bn + tx * 4] = o0;
            *(float4*)&P[(size_t)r * D_DICT + bn + 64 + tx * 4] = o1;
        }
    }
}

// ---------------------------------------------------------------------------
// Kernel 2 (v3): top-256, register-resident row. Row lives in 8 float4/thread;
// LDS holds only candidate pairs (+hist) -> ~9KB, no 32KB vals tile, no
// bank-conflicted LDS round-trip. Semantics identical to validated r7:
// Gaussian-tail pruning, margin check, full-radix fallback, exact band
// recompute in the np rounding class, ties -> lowest index.
// ---------------------------------------------------------------------------
__launch_bounds__(256)
__global__ void topk_band_kernel(const float* __restrict__ P,  // chunk-local
                                 int row0,
                                 const float* __restrict__ x,
                                 const float* __restrict__ Wenc,
                                 const float* __restrict__ b_enc,
                                 float* __restrict__ hidden) {
    __shared__ float  cand_val[CCAP];      // 4 KiB
    __shared__ int    cand_idx[CCAP];      // 4 KiB
    __shared__ uint32 hist[256];
    __shared__ float  redS[4], redS2[4];
    __shared__ float  sh_mu, sh_sig;
    __shared__ uint32 sh_prefix, sh_need;
    __shared__ int    sh_cnt, c_clear, bcnt;
    __shared__ int    bidx_s[BCAP];
    __shared__ float  bval_s[BCAP];

    int lrow = blockIdx.x;
    int grow = row0 + lrow;
    const float* p = P + (size_t)lrow * D_DICT;
    float* hrow = hidden + (size_t)grow * D_DICT;
    int t = threadIdx.x;

    // load row into registers, stats, zero-fill hidden
    float4 rv[8];
    float s = 0.f, s2 = 0.f;
    #pragma unroll
    for (int c = 0; c < 8; ++c) {
        int e4 = c * 256 + t;
        rv[c] = ((const float4*)p)[e4];
        s  += rv[c].x + rv[c].y + rv[c].z + rv[c].w;
        s2 += rv[c].x*rv[c].x + rv[c].y*rv[c].y + rv[c].z*rv[c].z + rv[c].w*rv[c].w;
        *(float4*)&hrow[e4 * 4] = make_float4(0.f, 0.f, 0.f, 0.f);
    }
    #pragma unroll
    for (int off = 32; off; off >>= 1) {
        s  += __shfl_down(s, off);
        s2 += __shfl_down(s2, off);
    }
    if ((t & 63) == 0) { redS[t >> 6] = s; redS2[t >> 6] = s2; }
    __syncthreads();
    if (t == 0) {
        float S  = redS[0] + redS[1] + redS[2] + redS[3];
        float S2 = redS2[0] + redS2[1] + redS2[2] + redS2[3];
        float mu = S * (1.f / D_DICT);
        float var = S2 * (1.f / D_DICT) - mu * mu;
        sh_mu = mu;
        sh_sig = sqrtf(fmaxf(var, 1e-20f));
    }
    __syncthreads();
    float mu = sh_mu, sig = sh_sig;

    // adaptive threshold from registers: TOPK <= cnt <= CCAP
    float z = 1.55f;
    float Tlo = 0.f;
    int n = 0;
    bool found = false;
    for (int a = 0; a < 6; ++a) {
        Tlo = mu + z * sig;
        if (t == 0) sh_cnt = 0;
        __syncthreads();
        int local = 0;
        #pragma unroll
        for (int c = 0; c < 8; ++c) {
            local += (rv[c].x > Tlo) ? 1 : 0;
            local += (rv[c].y > Tlo) ? 1 : 0;
            local += (rv[c].z > Tlo) ? 1 : 0;
            local += (rv[c].w > Tlo) ? 1 : 0;
        }
        #pragma unroll
        for (int off = 32; off; off >>= 1) local += __shfl_down(local, off);
        if ((t & 63) == 0) atomicAdd((uint32*)&sh_cnt, (uint32)local);
        __syncthreads();
        n = sh_cnt;
        if (n >= TOPK && n <= CCAP) { found = true; break; }
        z += (n < TOPK) ? -0.4f : 0.3f;
        __syncthreads();
    }

    // collect candidates into LDS pairs
    if (t == 0) sh_cnt = 0;
    __syncthreads();
    if (found) {
        #pragma unroll
        for (int c = 0; c < 8; ++c) {
            int base = (c * 256 + t) * 4;
            float vv[4] = {rv[c].x, rv[c].y, rv[c].z, rv[c].w};
            #pragma unroll
            for (int j = 0; j < 4; ++j) {
                if (vv[j] > Tlo) {
                    int slot = atomicAdd((uint32*)&sh_cnt, 1u);
                    if (slot < CCAP) { cand_val[slot] = vv[j]; cand_idx[slot] = base + j; }
                }
            }
        }
    }
    __syncthreads();

    // radix select (candidates, or full row from registers on fallback)
    float vT0 = 0.f;
    for (int rtry = 0; rtry < 2; ++rtry) {
        uint32 prefix = 0, need = TOPK;
        for (int pass = 0; pass < 4; ++pass) {
            int shift = 24 - 8 * pass;
            hist[t] = 0;
            __syncthreads();
            uint32 mask_hi = pass ? (0xFFFFFFFFu << (shift + 8)) : 0u;
            if (found) {
                for (int e = t; e < n; e += 256) {
                    uint32 u = okey(cand_val[e]);
                    if ((u & mask_hi) == prefix)
                        atomicAdd(&hist[(u >> shift) & 255u], 1u);
                }
            } else {
                #pragma unroll
                for (int c = 0; c < 8; ++c) {
                    float vv[4] = {rv[c].x, rv[c].y, rv[c].z, rv[c].w};
                    #pragma unroll
                    for (int j = 0; j < 4; ++j) {
                        uint32 u = okey(vv[j]);
                        if ((u & mask_hi) == prefix)
                            atomicAdd(&hist[(u >> shift) & 255u], 1u);
                    }
                }
            }
            __syncthreads();
            if (t == 0) {
                uint32 cum = 0;
                int d = 255;
                for (; d > 0; --d) {
                    uint32 h = hist[d];
                    if (cum + h >= need) break;
                    cum += h;
                }
                sh_prefix = prefix | ((uint32)d << shift);
                sh_need = need - cum;
            }
            __syncthreads();
            prefix = sh_prefix;
            need = sh_need;
            __syncthreads();
        }
        uint32 tb = (prefix & 0x80000000u) ? (prefix & 0x7FFFFFFFu) : ~prefix;
        vT0 = __uint_as_float(tb);
        if (!found) break;                       // fallback result is final
        if (vT0 - BAND - 1e-3f > Tlo) break;     // pruning provably safe
        found = false;                           // margin violated -> full radix
        __syncthreads();
    }

    // classify: clear winners write approx value; band entries -> exact list
    if (t == 0) { c_clear = 0; bcnt = 0; }
    __syncthreads();
    if (found) {
        for (int e = t; e < n; e += 256) {
            float v = cand_val[e];
            int i = cand_idx[e];
            if (v > vT0 + BAND) {
                hrow[i] = fmaxf(v, 0.f);
                atomicAdd((uint32*)&c_clear, 1u);
            } else if (v >= vT0 - BAND) {
                int slot = atomicAdd((uint32*)&bcnt, 1u);
                if (slot < BCAP) bidx_s[slot] = i;
            }
        }
    } else {
        #pragma unroll
        for (int c = 0; c < 8; ++c) {
            int base = (c * 256 + t) * 4;
            float vv[4] = {rv[c].x, rv[c].y, rv[c].z, rv[c].w};
            #pragma unroll
            for (int j = 0; j < 4; ++j) {
                float v = vv[j];
                if (v > vT0 + BAND) {
                    hrow[base + j] = fmaxf(v, 0.f);
                    atomicAdd((uint32*)&c_clear, 1u);
                } else if (v >= vT0 - BAND) {
                    int slot = atomicAdd((uint32*)&bcnt, 1u);
                    if (slot < BCAP) bidx_s[slot] = base + j;
                }
            }
        }
    }
    __syncthreads();

    // exact recompute of band entries (np rounding class: ascending-k fmaf)
    int nb = bcnt < BCAP ? bcnt : BCAP;
    if (t < nb) {
        const float* xr = x + (size_t)grow * D_IN;
        const float* wr = Wenc + (size_t)bidx_s[t] * D_IN;
        float acc = 0.f;
        #pragma unroll 8
        for (int k = 0; k < D_IN; ++k)   // ascending k — do not reorder
            acc = fmaf(xr[k], wr[k], acc);
        bval_s[t] = acc + b_enc[bidx_s[t]];
    }
    __syncthreads();
    if (t == 0) {
        int take = TOPK - c_clear;
        for (int rr = 0; rr < take; ++rr) {
            int best = -1; float bv = 0.f; int bi = 0;
            for (int e = 0; e < nb; ++e) {
                int idx = bidx_s[e];
                if (idx < 0) continue;
                float v = bval_s[e];
                if (best < 0 || v > bv || (v == bv && idx < bi)) {
                    best = e; bv = v; bi = idx;
                }
            }
            if (best < 0) break;
            bidx_s[best] = -1;
            hrow[bi] = fmaxf(bv, 0.f);
        }
    }
}

// ---------------------------------------------------------------------------
// Kernel 3: dense bf16 MFMA decode (validated rounds 5-7).
// ---------------------------------------------------------------------------
__launch_bounds__(512)
__global__ void mfma_decode_kernel(const float* __restrict__ hidden,
                                   const unsigned short* __restrict__ Wb,
                                   const float* __restrict__ b_dec,
                                   float* __restrict__ recon) {
    __shared__ unsigned short At[256 * 64];
    __shared__ unsigned short Bt[256 * 64];

    int tid  = threadIdx.x;
    int lane = tid & 63;
    int wid  = tid >> 6;
    int wm   = wid >> 2;
    int wn   = wid & 3;

    int bid = blockIdx.x;
    int bn  = (bid & 1) * 256;
    int bm  = (bid >> 1) * 256;

    f32x4 acc[8][4];
    #pragma unroll
    for (int i = 0; i < 8; ++i)
        #pragma unroll
        for (int j = 0; j < 4; ++j) acc[i][j] = (f32x4)0.f;

    for (int k0 = 0; k0 < D_DICT; k0 += 64) {
        #pragma unroll
        for (int i = 0; i < 8; ++i) {
            int idx = i * 512 + tid;
            int row = idx >> 4;
            int kq  = (idx & 15) * 4;
            float4 h4 = *(const float4*)&hidden[(size_t)(bm + row) * D_DICT + k0 + kq];
            us4 o;
            o.x = f2bf_rne(h4.x); o.y = f2bf_rne(h4.y);
            o.z = f2bf_rne(h4.z); o.w = f2bf_rne(h4.w);
            *(us4*)&At[swz(row, kq)] = o;
        }
        #pragma unroll
        for (int i = 0; i < 4; ++i) {
            int idx = i * 512 + tid;
            int row = idx >> 3;
            int kq8 = (idx & 7) * 8;
            us8 w8 = *(const us8*)&Wb[(size_t)(bn + row) * D_DICT + k0 + kq8];
            *(us8*)&Bt[swz(row, kq8)] = w8;
        }
        __syncthreads();

        #pragma unroll
        for (int ks = 0; ks < 2; ++ks) {
            int kb = ks * 32 + (lane >> 4) * 8;
            bf16x8 av[8], bv[4];
            #pragma unroll
            for (int mi = 0; mi < 8; ++mi)
                av[mi] = *(const bf16x8*)&At[swz(wm * 128 + mi * 16 + (lane & 15), kb)];
            #pragma unroll
            for (int nj = 0; nj < 4; ++nj)
                bv[nj] = *(const bf16x8*)&Bt[swz(wn * 64 + nj * 16 + (lane & 15), kb)];
            #pragma unroll
            for (int mi = 0; mi < 8; ++mi)
                #pragma unroll
                for (int nj = 0; nj < 4; ++nj)
                    acc[mi][nj] = __builtin_amdgcn_mfma_f32_16x16x32_bf16(
                        av[mi], bv[nj], acc[mi][nj], 0, 0, 0);
        }
        __syncthreads();
    }

    #pragma unroll
    for (int mi = 0; mi < 8; ++mi) {
        int r0 = bm + wm * 128 + mi * 16 + (lane >> 4) * 4;
        #pragma unroll
        for (int nj = 0; nj < 4; ++nj) {
            int col = bn + wn * 64 + nj * 16 + (lane & 15);
            float bd = b_dec[col];
            #pragma unroll
            for (int reg = 0; reg < 4; ++reg)
                recon[(size_t)(r0 + reg) * D_IN + col] = acc[mi][nj][reg] + bd;
        }
    }
}

// ---------------------------------------------------------------------------
// Kernel 3b: exact gather decode (tiny-ws fallback)
// ---------------------------------------------------------------------------
__launch_bounds__(256)
__global__ void decode_direct_kernel(const float* __restrict__ hidden,
                                     const float* __restrict__ W_dec,
                                     const float* __restrict__ b_dec,
                                     float* __restrict__ recon) {
    __shared__ float  sv[TOPK];
    __shared__ int    sidx[TOPK];
    __shared__ int    offs[257];
    int row = blockIdx.x;
    int t = threadIdx.x;
    const float* hrow = hidden + (size_t)row * D_DICT;

    int base = t * 32;
    int c = 0;
    for (int j = 0; j < 32; ++j) c += (hrow[base + j] > 0.f) ? 1 : 0;
    offs[t + 1] = c;
    __syncthreads();
    if (t == 0) {
        offs[0] = 0;
        for (int i = 0; i < 256; ++i) offs[i + 1] += offs[i];
    }
    __syncthreads();
    int o = offs[t];
    for (int j = 0; j < 32; ++j) {
        float v = hrow[base + j];
        if (v > 0.f) { sv[o] = v; sidx[o] = base + j; ++o; }
    }
    __syncthreads();
    int total = offs[256];

    int d0 = 2 * t;
    float acc0 = b_dec[d0];
    float acc1 = b_dec[d0 + 1];
    for (int k = 0; k < total; ++k) {
        float v = sv[k];
        int idx = sidx[k];
        acc0 = fmaf(v, W_dec[(size_t)d0 * D_DICT + idx], acc0);
        acc1 = fmaf(v, W_dec[(size_t)(d0 + 1) * D_DICT + idx], acc1);
    }
    *(float2*)&recon[(size_t)row * D_IN + d0] = make_float2(acc0, acc1);
}

// ---------------------------------------------------------------------------
extern "C" void kernel_launch(void* const* d_in, const int* in_sizes, int n_in,
                              void* d_out, int out_size, void* d_ws, size_t ws_size,
                              hipStream_t stream) {
    const float* x     = (const float*)d_in[0];
    const float* W_enc = (const float*)d_in[1];
    const float* b_enc = (const float*)d_in[2];
    const float* W_dec = (const float*)d_in[3];
    const float* b_dec = (const float*)d_in[4];

    float* out    = (float*)d_out;
    float* recon  = out;                          // 16384*512 fp32
    float* hidden = out + (size_t)N_ROWS * D_IN;  // 16384*8192 fp32

    const size_t WB_BYTES  = (size_t)D_IN * D_DICT * sizeof(unsigned short); // 8 MiB
    const size_t ROW_BYTES = (size_t)D_DICT * sizeof(float);                 // 32 KiB

    char* ws = (char*)d_ws;

    if (ws_size >= WB_BYTES + 256 * ROW_BYTES) {
        // Tier B: MFMA encode + MFMA decode
        unsigned short* Wb  = (unsigned short*)ws;
        float*          pre = (float*)(ws + WB_BYTES);
        size_t avail = ws_size - WB_BYTES;

        long long cl = (long long)(avail / ROW_BYTES);
        int chunk = (cl > N_ROWS) ? N_ROWS : (int)cl;
        chunk &= ~255;

        cast_wdec_kernel<<<(D_IN * D_DICT) / 1024, 256, 0, stream>>>(W_dec, Wb);

        for (int r0 = 0; r0 < N_ROWS; r0 += chunk) {
            int nr = (N_ROWS - r0 < chunk) ? (N_ROWS - r0) : chunk;
            encode_mfma_kernel<<<dim3(nr / 256, D_DICT / 256), 512, 0, stream>>>(
                x, W_enc, b_enc, pre, r0);
            topk_band_kernel<<<nr, 256, 0, stream>>>(pre, r0, x, W_enc, b_enc, hidden);
        }

        mfma_decode_kernel<<<(N_ROWS / 256) * 2, 512, 0, stream>>>(hidden, Wb, b_dec, recon);
    } else {
        // Tier C: exact fp32 encode + gather decode (tiny ws)
        float* pre = (float*)ws;
        long long cl = (long long)(ws_size / ROW_BYTES);
        int chunk;
        if (cl >= 128) { chunk = (cl > 2048) ? 2048 : (int)cl; chunk &= ~127; }
        else chunk = (cl < 1) ? 1 : (int)cl;

        for (int r0 = 0; r0 < N_ROWS; r0 += chunk) {
            int nr = (N_ROWS - r0 < chunk) ? (N_ROWS - r0) : chunk;
            dim3 grid((nr + 127) / 128, D_DICT / 128);
            encode_gemm_kernel<<<grid, 256, 0, stream>>>(x, W_enc, b_enc, pre, r0, nr);
            topk_band_kernel<<<nr, 256, 0, stream>>>(pre, r0, x, W_enc, b_enc, hidden);
        }
        decode_direct_kernel<<<N_ROWS, 256, 0, stream>>>(hidden, W_dec, b_dec, recon);
    }
}

// Round 9
// 1591.889 us; speedup vs baseline: 2.3842x; 2.3842x over previous
//
#include <hip/hip_runtime.h>

typedef unsigned int uint32;
typedef __attribute__((ext_vector_type(4))) float  f32x4;
typedef __attribute__((ext_vector_type(8))) short  bf16x8;
typedef __attribute__((ext_vector_type(4))) unsigned short us4;
typedef __attribute__((ext_vector_type(8))) unsigned short us8;

#define N_ROWS   16384
#define D_IN     512
#define D_DICT   8192
#define TOPK     256
#define BAND     2e-3f
#define BCAP     64
#define CCAP     2048

__device__ __forceinline__ unsigned short f2bf_rne(float f) {
    unsigned u = __float_as_uint(f);
    unsigned r = u + 0x7FFFu + ((u >> 16) & 1u);
    return (unsigned short)(r >> 16);
}
__device__ __forceinline__ float bf2f(unsigned short h) {
    return __uint_as_float(((unsigned)h) << 16);
}
__device__ __forceinline__ uint32 okey(float v) {
    uint32 u = __float_as_uint(v);
    return (u & 0x80000000u) ? ~u : (u | 0x80000000u);
}
// XOR-swizzled LDS element address for [256][64] bf16 tiles (validated r5-r8)
__device__ __forceinline__ int swz(int row, int k) {
    return row * 64 + (k ^ ((row & 7) << 3));
}

// ---------------------------------------------------------------------------
// Kernel 0: cast W_dec [512][8192] fp32 -> bf16 (same layout) into ws
// ---------------------------------------------------------------------------
__launch_bounds__(256)
__global__ void cast_wdec_kernel(const float* __restrict__ W,
                                 unsigned short* __restrict__ Wb) {
    size_t i = ((size_t)blockIdx.x * 256 + threadIdx.x) * 4;
    float4 v = *(const float4*)&W[i];
    us4 o;
    o.x = f2bf_rne(v.x); o.y = f2bf_rne(v.y);
    o.z = f2bf_rne(v.z); o.w = f2bf_rne(v.w);
    *(us4*)&Wb[i] = o;
}

// ---------------------------------------------------------------------------
// Kernel 1: MFMA encode via 3-term bf16 split (validated rounds 6-8).
// ---------------------------------------------------------------------------
__launch_bounds__(512)
__global__ void encode_mfma_kernel(const float* __restrict__ x,
                                   const float* __restrict__ Wenc,
                                   const float* __restrict__ b_enc,
                                   float* __restrict__ P,   // chunk-local
                                   int row0) {
    __shared__ unsigned short At[256 * 64];
    __shared__ unsigned short Bt[256 * 64];

    int tid  = threadIdx.x;
    int lane = tid & 63;
    int wid  = tid >> 6;
    int wm   = wid >> 2;
    int wn   = wid & 3;
    int bm   = blockIdx.x * 256;
    int bn   = blockIdx.y * 256;
    int fr   = lane & 15;
    int fk   = (lane >> 4) << 3;

    f32x4 acc[8][4];
    #pragma unroll
    for (int i = 0; i < 8; ++i)
        #pragma unroll
        for (int j = 0; j < 4; ++j) acc[i][j] = (f32x4)0.f;

    int srow = tid >> 1;
    int skb  = (tid & 1) << 4;

    for (int k0 = 0; k0 < D_IN; k0 += 32) {
        {
            const float* ax = x + (size_t)(row0 + bm + srow) * D_IN + k0 + skb;
            float4 a0 = ((const float4*)ax)[0];
            float4 a1 = ((const float4*)ax)[1];
            float4 a2 = ((const float4*)ax)[2];
            float4 a3 = ((const float4*)ax)[3];
            float av[16] = {a0.x,a0.y,a0.z,a0.w, a1.x,a1.y,a1.z,a1.w,
                            a2.x,a2.y,a2.z,a2.w, a3.x,a3.y,a3.z,a3.w};
            us8 h0, h1, l0, l1;
            #pragma unroll
            for (int j = 0; j < 8; ++j) {
                unsigned short hh = f2bf_rne(av[j]);
                h0[j] = hh; l0[j] = f2bf_rne(av[j] - bf2f(hh));
            }
            #pragma unroll
            for (int j = 0; j < 8; ++j) {
                unsigned short hh = f2bf_rne(av[8 + j]);
                h1[j] = hh; l1[j] = f2bf_rne(av[8 + j] - bf2f(hh));
            }
            *(us8*)&At[swz(srow, skb)]          = h0;
            *(us8*)&At[swz(srow, skb + 8)]      = h1;
            *(us8*)&At[swz(srow, 32 + skb)]     = l0;
            *(us8*)&At[swz(srow, 32 + skb + 8)] = l1;
        }
        {
            const float* bx = Wenc + (size_t)(bn + srow) * D_IN + k0 + skb;
            float4 b0 = ((const float4*)bx)[0];
            float4 b1 = ((const float4*)bx)[1];
            float4 b2 = ((const float4*)bx)[2];
            float4 b3 = ((const float4*)bx)[3];
            float bv[16] = {b0.x,b0.y,b0.z,b0.w, b1.x,b1.y,b1.z,b1.w,
                            b2.x,b2.y,b2.z,b2.w, b3.x,b3.y,b3.z,b3.w};
            us8 h0, h1, l0, l1;
            #pragma unroll
            for (int j = 0; j < 8; ++j) {
                unsigned short hh = f2bf_rne(bv[j]);
                h0[j] = hh; l0[j] = f2bf_rne(bv[j] - bf2f(hh));
            }
            #pragma unroll
            for (int j = 0; j < 8; ++j) {
                unsigned short hh = f2bf_rne(bv[8 + j]);
                h1[j] = hh; l1[j] = f2bf_rne(bv[8 + j] - bf2f(hh));
            }
            *(us8*)&Bt[swz(srow, skb)]          = h0;
            *(us8*)&Bt[swz(srow, skb + 8)]      = h1;
            *(us8*)&Bt[swz(srow, 32 + skb)]     = l0;
            *(us8*)&Bt[swz(srow, 32 + skb + 8)] = l1;
        }
        __syncthreads();

        bf16x8 bh[4], bl[4];
        #pragma unroll
        for (int nj = 0; nj < 4; ++nj) {
            bh[nj] = *(const bf16x8*)&Bt[swz(wn * 64 + nj * 16 + fr, fk)];
            bl[nj] = *(const bf16x8*)&Bt[swz(wn * 64 + nj * 16 + fr, 32 + fk)];
        }
        #pragma unroll
        for (int mi = 0; mi < 8; ++mi) {
            bf16x8 ah = *(const bf16x8*)&At[swz(wm * 128 + mi * 16 + fr, fk)];
            bf16x8 al = *(const bf16x8*)&At[swz(wm * 128 + mi * 16 + fr, 32 + fk)];
            #pragma unroll
            for (int nj = 0; nj < 4; ++nj) {
                acc[mi][nj] = __builtin_amdgcn_mfma_f32_16x16x32_bf16(ah, bh[nj], acc[mi][nj], 0, 0, 0);
                acc[mi][nj] = __builtin_amdgcn_mfma_f32_16x16x32_bf16(ah, bl[nj], acc[mi][nj], 0, 0, 0);
                acc[mi][nj] = __builtin_amdgcn_mfma_f32_16x16x32_bf16(al, bh[nj], acc[mi][nj], 0, 0, 0);
            }
        }
        __syncthreads();
    }

    #pragma unroll
    for (int mi = 0; mi < 8; ++mi) {
        int r0 = bm + wm * 128 + mi * 16 + (lane >> 4) * 4;
        #pragma unroll
        for (int nj = 0; nj < 4; ++nj) {
            int col = bn + wn * 64 + nj * 16 + fr;
            float bd = b_enc[col];
            #pragma unroll
            for (int reg = 0; reg < 4; ++reg)
                P[(size_t)(r0 + reg) * D_DICT + col] = acc[mi][nj][reg] + bd;
        }
    }
}

// ---------------------------------------------------------------------------
// Kernel 1b (fallback): exact fp32 encode GEMM (np rounding class).
// ---------------------------------------------------------------------------
#define EBK 8
#define ESTR 132

__launch_bounds__(256)
__global__ void encode_gemm_kernel(const float* __restrict__ X,
                                   const float* __restrict__ Wenc,
                                   const float* __restrict__ b_enc,
                                   float* __restrict__ P,
                                   int row0, int nrows) {
    __shared__ float As[EBK][ESTR];
    __shared__ float Bs[EBK][ESTR];
    int tid = threadIdx.x;
    int tx = tid & 15;
    int ty = tid >> 4;
    int bm = blockIdx.x * 128;
    int bn = blockIdx.y * 128;
    int srow = tid >> 1;
    int skq  = (tid & 1) * 4;

    float acc[8][8];
    #pragma unroll
    for (int i = 0; i < 8; ++i)
        #pragma unroll
        for (int j = 0; j < 8; ++j) acc[i][j] = 0.f;

    for (int k0 = 0; k0 < D_IN; k0 += EBK) {
        float4 a4 = make_float4(0.f, 0.f, 0.f, 0.f);
        if (bm + srow < nrows)
            a4 = *(const float4*)&X[(size_t)(row0 + bm + srow) * D_IN + k0 + skq];
        float4 b4 = *(const float4*)&Wenc[(size_t)(bn + srow) * D_IN + k0 + skq];
        As[skq + 0][srow] = a4.x; As[skq + 1][srow] = a4.y;
        As[skq + 2][srow] = a4.z; As[skq + 3][srow] = a4.w;
        Bs[skq + 0][srow] = b4.x; Bs[skq + 1][srow] = b4.y;
        Bs[skq + 2][srow] = b4.z; Bs[skq + 3][srow] = b4.w;
        __syncthreads();
        #pragma unroll
        for (int k = 0; k < EBK; ++k) {
            float4 a0 = *(const float4*)&As[k][ty * 4];
            float4 a1 = *(const float4*)&As[k][64 + ty * 4];
            float4 b0 = *(const float4*)&Bs[k][tx * 4];
            float4 b1 = *(const float4*)&Bs[k][64 + tx * 4];
            float a[8] = {a0.x, a0.y, a0.z, a0.w, a1.x, a1.y, a1.z, a1.w};
            float b[8] = {b0.x, b0.y, b0.z, b0.w, b1.x, b1.y, b1.z, b1.w};
            #pragma unroll
            for (int i = 0; i < 8; ++i)
                #pragma unroll
                for (int j = 0; j < 8; ++j)
                    acc[i][j] = fmaf(a[i], b[j], acc[i][j]);
        }
        __syncthreads();
    }

    float4 bias0 = *(const float4*)&b_enc[bn + tx * 4];
    float4 bias1 = *(const float4*)&b_enc[bn + 64 + tx * 4];
    float bb[8] = {bias0.x, bias0.y, bias0.z, bias0.w,
                   bias1.x, bias1.y, bias1.z, bias1.w};
    #pragma unroll
    for (int i = 0; i < 8; ++i) {
        int r = bm + (i < 4 ? ty * 4 + i : 64 + ty * 4 + (i - 4));
        if (r < nrows) {
            float4 o0, o1;
            o0.x = acc[i][0] + bb[0]; o0.y = acc[i][1] + bb[1];
            o0.z = acc[i][2] + bb[2]; o0.w = acc[i][3] + bb[3];
            o1.x = acc[i][4] + bb[4]; o1.y = acc[i][5] + bb[5];
            o1.z = acc[i][6] + bb[6]; o1.w = acc[i][7] + bb[7];
            *(float4*)&P[(size_t)r * D_DICT + bn + tx * 4] = o0;
            *(float4*)&P[(size_t)r * D_DICT + bn + 64 + tx * 4] = o1;
        }
    }
}

// ---------------------------------------------------------------------------
// Kernel 2 (v4): top-256, streaming row (no vals tile, no register residency).
// Pass 1: stats + zero-fill hidden. Pass 2: collect candidates at fixed
// z=1.3 (E[n]=793, sd=27; [256,2048] bounds are >20 sigma -> no adaptive
// loop). Radix + classify run over LDS candidates only. LDS ~18KB ->
// 8 blocks/CU; VGPR low (row never register-resident; r8 lesson).
// Exact semantics preserved: margin check, full-radix-from-global fallback,
// band recompute in np rounding class (ascending-k fmaf), ties -> lowest idx.
// ---------------------------------------------------------------------------
__launch_bounds__(256)
__global__ void topk_band_kernel(const float* __restrict__ P,  // chunk-local
                                 int row0,
                                 const float* __restrict__ x,
                                 const float* __restrict__ Wenc,
                                 const float* __restrict__ b_enc,
                                 float* __restrict__ hidden) {
    __shared__ float  cand_val[CCAP];      // 8 KiB
    __shared__ int    cand_idx[CCAP];      // 8 KiB
    __shared__ uint32 hist[256];           // 1 KiB
    __shared__ float  redS[4], redS2[4];
    __shared__ float  sh_mu, sh_sig;
    __shared__ uint32 sh_prefix, sh_need;
    __shared__ int    sh_cnt, c_clear, bcnt;
    __shared__ int    bidx_s[BCAP];
    __shared__ float  bval_s[BCAP];

    int lrow = blockIdx.x;
    int grow = row0 + lrow;
    const float* p = P + (size_t)lrow * D_DICT;
    float* hrow = hidden + (size_t)grow * D_DICT;
    int t = threadIdx.x;

    // pass 1: stats + zero-fill hidden (row NOT kept resident)
    float s = 0.f, s2 = 0.f;
    #pragma unroll 2
    for (int c = 0; c < 8; ++c) {
        int e4 = c * 256 + t;
        float4 v4 = ((const float4*)p)[e4];
        s  += v4.x + v4.y + v4.z + v4.w;
        s2 += v4.x*v4.x + v4.y*v4.y + v4.z*v4.z + v4.w*v4.w;
        *(float4*)&hrow[e4 * 4] = make_float4(0.f, 0.f, 0.f, 0.f);
    }
    #pragma unroll
    for (int off = 32; off; off >>= 1) {
        s  += __shfl_down(s, off);
        s2 += __shfl_down(s2, off);
    }
    if ((t & 63) == 0) { redS[t >> 6] = s; redS2[t >> 6] = s2; }
    if (t == 0) sh_cnt = 0;
    __syncthreads();
    if (t == 0) {
        float S  = redS[0] + redS[1] + redS[2] + redS[3];
        float S2 = redS2[0] + redS2[1] + redS2[2] + redS2[3];
        float mu = S * (1.f / D_DICT);
        float var = S2 * (1.f / D_DICT) - mu * mu;
        sh_mu = mu;
        sh_sig = sqrtf(fmaxf(var, 1e-20f));
    }
    __syncthreads();
    float Tlo = sh_mu + 1.3f * sh_sig;

    // pass 2: collect candidates (re-read from L2)
    #pragma unroll 2
    for (int c = 0; c < 8; ++c) {
        int e4 = c * 256 + t;
        float4 v4 = ((const float4*)p)[e4];
        float vv[4] = {v4.x, v4.y, v4.z, v4.w};
        #pragma unroll
        for (int j = 0; j < 4; ++j) {
            if (vv[j] > Tlo) {
                int slot = atomicAdd((uint32*)&sh_cnt, 1u);
                if (slot < CCAP) { cand_val[slot] = vv[j]; cand_idx[slot] = e4 * 4 + j; }
            }
        }
    }
    __syncthreads();
    int n = sh_cnt;
    bool found = (n >= TOPK && n <= CCAP);

    // radix select (candidates; full-global fallback if pruning unsafe)
    float vT0 = 0.f;
    for (int rtry = 0; rtry < 2; ++rtry) {
        uint32 prefix = 0, need = TOPK;
        for (int pass = 0; pass < 4; ++pass) {
            int shift = 24 - 8 * pass;
            hist[t] = 0;
            __syncthreads();
            uint32 mask_hi = pass ? (0xFFFFFFFFu << (shift + 8)) : 0u;
            if (found) {
                for (int e = t; e < n; e += 256) {
                    uint32 u = okey(cand_val[e]);
                    if ((u & mask_hi) == prefix)
                        atomicAdd(&hist[(u >> shift) & 255u], 1u);
                }
            } else {
                for (int e = t; e < D_DICT; e += 256) {
                    uint32 u = okey(p[e]);
                    if ((u & mask_hi) == prefix)
                        atomicAdd(&hist[(u >> shift) & 255u], 1u);
                }
            }
            __syncthreads();
            if (t == 0) {
                uint32 cum = 0;
                int d = 255;
                for (; d > 0; --d) {
                    uint32 h = hist[d];
                    if (cum + h >= need) break;
                    cum += h;
                }
                sh_prefix = prefix | ((uint32)d << shift);
                sh_need = need - cum;
            }
            __syncthreads();
            prefix = sh_prefix;
            need = sh_need;
            __syncthreads();
        }
        uint32 tb = (prefix & 0x80000000u) ? (prefix & 0x7FFFFFFFu) : ~prefix;
        vT0 = __uint_as_float(tb);
        if (!found) break;                       // fallback result is final
        if (vT0 - BAND - 1e-3f > Tlo) break;     // pruning provably safe
        found = false;                           // margin violated -> full radix
        __syncthreads();
    }

    // classify: clear winners write approx value; band entries -> exact list
    if (t == 0) { c_clear = 0; bcnt = 0; }
    __syncthreads();
    if (found) {
        for (int e = t; e < n; e += 256) {
            float v = cand_val[e];
            int i = cand_idx[e];
            if (v > vT0 + BAND) {
                hrow[i] = fmaxf(v, 0.f);
                atomicAdd((uint32*)&c_clear, 1u);
            } else if (v >= vT0 - BAND) {
                int slot = atomicAdd((uint32*)&bcnt, 1u);
                if (slot < BCAP) bidx_s[slot] = i;
            }
        }
    } else {
        for (int e = t; e < D_DICT; e += 256) {
            float v = p[e];
            if (v > vT0 + BAND) {
                hrow[e] = fmaxf(v, 0.f);
                atomicAdd((uint32*)&c_clear, 1u);
            } else if (v >= vT0 - BAND) {
                int slot = atomicAdd((uint32*)&bcnt, 1u);
                if (slot < BCAP) bidx_s[slot] = e;
            }
        }
    }
    __syncthreads();

    // exact recompute of band entries (np rounding class: ascending-k fmaf)
    int nb = bcnt < BCAP ? bcnt : BCAP;
    if (t < nb) {
        const float* xr = x + (size_t)grow * D_IN;
        const float* wr = Wenc + (size_t)bidx_s[t] * D_IN;
        float acc = 0.f;
        #pragma unroll 8
        for (int k = 0; k < D_IN; ++k)   // ascending k — do not reorder
            acc = fmaf(xr[k], wr[k], acc);
        bval_s[t] = acc + b_enc[bidx_s[t]];
    }
    __syncthreads();
    if (t == 0) {
        int take = TOPK - c_clear;
        for (int rr = 0; rr < take; ++rr) {
            int best = -1; float bv = 0.f; int bi = 0;
            for (int e = 0; e < nb; ++e) {
                int idx = bidx_s[e];
                if (idx < 0) continue;
                float v = bval_s[e];
                if (best < 0 || v > bv || (v == bv && idx < bi)) {
                    best = e; bv = v; bi = idx;
                }
            }
            if (best < 0) break;
            bidx_s[best] = -1;
            hrow[bi] = fmaxf(bv, 0.f);
        }
    }
}

// ---------------------------------------------------------------------------
// Kernel 3: dense bf16 MFMA decode (validated rounds 5-8).
// ---------------------------------------------------------------------------
__launch_bounds__(512)
__global__ void mfma_decode_kernel(const float* __restrict__ hidden,
                                   const unsigned short* __restrict__ Wb,
                                   const float* __restrict__ b_dec,
                                   float* __restrict__ recon) {
    __shared__ unsigned short At[256 * 64];
    __shared__ unsigned short Bt[256 * 64];

    int tid  = threadIdx.x;
    int lane = tid & 63;
    int wid  = tid >> 6;
    int wm   = wid >> 2;
    int wn   = wid & 3;

    int bid = blockIdx.x;
    int bn  = (bid & 1) * 256;
    int bm  = (bid >> 1) * 256;

    f32x4 acc[8][4];
    #pragma unroll
    for (int i = 0; i < 8; ++i)
        #pragma unroll
        for (int j = 0; j < 4; ++j) acc[i][j] = (f32x4)0.f;

    for (int k0 = 0; k0 < D_DICT; k0 += 64) {
        #pragma unroll
        for (int i = 0; i < 8; ++i) {
            int idx = i * 512 + tid;
            int row = idx >> 4;
            int kq  = (idx & 15) * 4;
            float4 h4 = *(const float4*)&hidden[(size_t)(bm + row) * D_DICT + k0 + kq];
            us4 o;
            o.x = f2bf_rne(h4.x); o.y = f2bf_rne(h4.y);
            o.z = f2bf_rne(h4.z); o.w = f2bf_rne(h4.w);
            *(us4*)&At[swz(row, kq)] = o;
        }
        #pragma unroll
        for (int i = 0; i < 4; ++i) {
            int idx = i * 512 + tid;
            int row = idx >> 3;
            int kq8 = (idx & 7) * 8;
            us8 w8 = *(const us8*)&Wb[(size_t)(bn + row) * D_DICT + k0 + kq8];
            *(us8*)&Bt[swz(row, kq8)] = w8;
        }
        __syncthreads();

        #pragma unroll
        for (int ks = 0; ks < 2; ++ks) {
            int kb = ks * 32 + (lane >> 4) * 8;
            bf16x8 av[8], bv[4];
            #pragma unroll
            for (int mi = 0; mi < 8; ++mi)
                av[mi] = *(const bf16x8*)&At[swz(wm * 128 + mi * 16 + (lane & 15), kb)];
            #pragma unroll
            for (int nj = 0; nj < 4; ++nj)
                bv[nj] = *(const bf16x8*)&Bt[swz(wn * 64 + nj * 16 + (lane & 15), kb)];
            #pragma unroll
            for (int mi = 0; mi < 8; ++mi)
                #pragma unroll
                for (int nj = 0; nj < 4; ++nj)
                    acc[mi][nj] = __builtin_amdgcn_mfma_f32_16x16x32_bf16(
                        av[mi], bv[nj], acc[mi][nj], 0, 0, 0);
        }
        __syncthreads();
    }

    #pragma unroll
    for (int mi = 0; mi < 8; ++mi) {
        int r0 = bm + wm * 128 + mi * 16 + (lane >> 4) * 4;
        #pragma unroll
        for (int nj = 0; nj < 4; ++nj) {
            int col = bn + wn * 64 + nj * 16 + (lane & 15);
            float bd = b_dec[col];
            #pragma unroll
            for (int reg = 0; reg < 4; ++reg)
                recon[(size_t)(r0 + reg) * D_IN + col] = acc[mi][nj][reg] + bd;
        }
    }
}

// ---------------------------------------------------------------------------
// Kernel 3b: exact gather decode (tiny-ws fallback)
// ---------------------------------------------------------------------------
__launch_bounds__(256)
__global__ void decode_direct_kernel(const float* __restrict__ hidden,
                                     const float* __restrict__ W_dec,
                                     const float* __restrict__ b_dec,
                                     float* __restrict__ recon) {
    __shared__ float  sv[TOPK];
    __shared__ int    sidx[TOPK];
    __shared__ int    offs[257];
    int row = blockIdx.x;
    int t = threadIdx.x;
    const float* hrow = hidden + (size_t)row * D_DICT;

    int base = t * 32;
    int c = 0;
    for (int j = 0; j < 32; ++j) c += (hrow[base + j] > 0.f) ? 1 : 0;
    offs[t + 1] = c;
    __syncthreads();
    if (t == 0) {
        offs[0] = 0;
        for (int i = 0; i < 256; ++i) offs[i + 1] += offs[i];
    }
    __syncthreads();
    int o = offs[t];
    for (int j = 0; j < 32; ++j) {
        float v = hrow[base + j];
        if (v > 0.f) { sv[o] = v; sidx[o] = base + j; ++o; }
    }
    __syncthreads();
    int total = offs[256];

    int d0 = 2 * t;
    float acc0 = b_dec[d0];
    float acc1 = b_dec[d0 + 1];
    for (int k = 0; k < total; ++k) {
        float v = sv[k];
        int idx = sidx[k];
        acc0 = fmaf(v, W_dec[(size_t)d0 * D_DICT + idx], acc0);
        acc1 = fmaf(v, W_dec[(size_t)(d0 + 1) * D_DICT + idx], acc1);
    }
    *(float2*)&recon[(size_t)row * D_IN + d0] = make_float2(acc0, acc1);
}

// ---------------------------------------------------------------------------
extern "C" void kernel_launch(void* const* d_in, const int* in_sizes, int n_in,
                              void* d_out, int out_size, void* d_ws, size_t ws_size,
                              hipStream_t stream) {
    const float* x     = (const float*)d_in[0];
    const float* W_enc = (const float*)d_in[1];
    const float* b_enc = (const float*)d_in[2];
    const float* W_dec = (const float*)d_in[3];
    const float* b_dec = (const float*)d_in[4];

    float* out    = (float*)d_out;
    float* recon  = out;                          // 16384*512 fp32
    float* hidden = out + (size_t)N_ROWS * D_IN;  // 16384*8192 fp32

    const size_t WB_BYTES  = (size_t)D_IN * D_DICT * sizeof(unsigned short); // 8 MiB
    const size_t ROW_BYTES = (size_t)D_DICT * sizeof(float);                 // 32 KiB

    char* ws = (char*)d_ws;

    if (ws_size >= WB_BYTES + 256 * ROW_BYTES) {
        // Tier B: MFMA encode + MFMA decode
        unsigned short* Wb  = (unsigned short*)ws;
        float*          pre = (float*)(ws + WB_BYTES);
        size_t avail = ws_size - WB_BYTES;

        long long cl = (long long)(avail / ROW_BYTES);
        int chunk = (cl > N_ROWS) ? N_ROWS : (int)cl;
        chunk &= ~255;

        cast_wdec_kernel<<<(D_IN * D_DICT) / 1024, 256, 0, stream>>>(W_dec, Wb);

        for (int r0 = 0; r0 < N_ROWS; r0 += chunk) {
            int nr = (N_ROWS - r0 < chunk) ? (N_ROWS - r0) : chunk;
            encode_mfma_kernel<<<dim3(nr / 256, D_DICT / 256), 512, 0, stream>>>(
                x, W_enc, b_enc, pre, r0);
            topk_band_kernel<<<nr, 256, 0, stream>>>(pre, r0, x, W_enc, b_enc, hidden);
        }

        mfma_decode_kernel<<<(N_ROWS / 256) * 2, 512, 0, stream>>>(hidden, Wb, b_dec, recon);
    } else {
        // Tier C: exact fp32 encode + gather decode (tiny ws)
        float* pre = (float*)ws;
        long long cl = (long long)(ws_size / ROW_BYTES);
        int chunk;
        if (cl >= 128) { chunk = (cl > 2048) ? 2048 : (int)cl; chunk &= ~127; }
        else chunk = (cl < 1) ? 1 : (int)cl;

        for (int r0 = 0; r0 < N_ROWS; r0 += chunk) {
            int nr = (N_ROWS - r0 < chunk) ? (N_ROWS - r0) : chunk;
            dim3 grid((nr + 127) / 128, D_DICT / 128);
            encode_gemm_kernel<<<grid, 256, 0, stream>>>(x, W_enc, b_enc, pre, r0, nr);
            topk_band_kernel<<<nr, 256, 0, stream>>>(pre, r0, x, W_enc, b_enc, hidden);
        }
        decode_direct_kernel<<<N_ROWS, 256, 0, stream>>>(hidden, W_dec, b_dec, recon);
    }
}

// Round 10
// 1558.725 us; speedup vs baseline: 2.4349x; 1.0213x over previous
//
#include <hip/hip_runtime.h>

typedef unsigned int uint32;
typedef __attribute__((ext_vector_type(4))) float  f32x4;
typedef __attribute__((ext_vector_type(8))) short  bf16x8;
typedef __attribute__((ext_vector_type(4))) unsigned short us4;
typedef __attribute__((ext_vector_type(8))) unsigned short us8;

#define N_ROWS   16384
#define D_IN     512
#define D_DICT   8192
#define TOPK     256
#define BAND     2e-3f
#define BCAP     64
#define CCAP     2048

__device__ __forceinline__ unsigned short f2bf_rne(float f) {
    unsigned u = __float_as_uint(f);
    unsigned r = u + 0x7FFFu + ((u >> 16) & 1u);
    return (unsigned short)(r >> 16);
}
__device__ __forceinline__ float bf2f(unsigned short h) {
    return __uint_as_float(((unsigned)h) << 16);
}
__device__ __forceinline__ uint32 okey(float v) {
    uint32 u = __float_as_uint(v);
    return (u & 0x80000000u) ? ~u : (u | 0x80000000u);
}
// XOR-swizzled LDS element address for [256][64] bf16 tiles (validated r5-r9)
__device__ __forceinline__ int swz(int row, int k) {
    return row * 64 + (k ^ ((row & 7) << 3));
}

// ---------------------------------------------------------------------------
// Kernel 0a: cast W_dec [512][8192] fp32 -> bf16 (same layout) into ws
// ---------------------------------------------------------------------------
__launch_bounds__(256)
__global__ void cast_wdec_kernel(const float* __restrict__ W,
                                 unsigned short* __restrict__ Wb) {
    size_t i = ((size_t)blockIdx.x * 256 + threadIdx.x) * 4;
    float4 v = *(const float4*)&W[i];
    us4 o;
    o.x = f2bf_rne(v.x); o.y = f2bf_rne(v.y);
    o.z = f2bf_rne(v.z); o.w = f2bf_rne(v.w);
    *(us4*)&Wb[i] = o;
}

// ---------------------------------------------------------------------------
// Kernel 0b: pre-split a [nrows][512] fp32 matrix into [nrows][16][64] bf16
// (per 32-K chunk: hi(0..31) | lo(32..63)) with the per-row XOR swizzle baked
// in: physical 8-elem group g holds logical group g ^ (row&7). Staging in
// encode then becomes LINEAR 16B copies; values bitwise match r9's
// split-on-stage (same f2bf_rne chain) so P is unchanged.
// ---------------------------------------------------------------------------
__launch_bounds__(256)
__global__ void split_hilo_kernel(const float* __restrict__ W,
                                  unsigned short* __restrict__ S) {
    int idx = blockIdx.x * 256 + threadIdx.x;   // (row, chunk)
    int row = idx >> 4;
    int c   = idx & 15;
    const float* src = W + (size_t)row * D_IN + c * 32;
    unsigned short hi[32], lo[32];
    #pragma unroll
    for (int j = 0; j < 32; ++j) {
        float v = src[j];
        unsigned short h = f2bf_rne(v);
        hi[j] = h; lo[j] = f2bf_rne(v - bf2f(h));
    }
    int m = row & 7;
    unsigned short* dst = S + ((size_t)row * 16 + c) * 64;
    #pragma unroll
    for (int g = 0; g < 8; ++g) {
        int lg = g ^ m;           // logical group stored at physical g
        us8 o;
        #pragma unroll
        for (int j = 0; j < 8; ++j)
            o[j] = (lg < 4) ? hi[lg * 8 + j] : lo[(lg - 4) * 8 + j];
        *(us8*)&dst[g * 8] = o;
    }
}

// ---------------------------------------------------------------------------
// Kernel 1: MFMA encode (3-term bf16 split, presplit inputs). Staging is
// linear us8 copies from Xs/Ws (swizzle pre-baked). Epilogue additionally
// accumulates per-row sum/sum^2 into global stats (for single-pass topk).
// ---------------------------------------------------------------------------
__launch_bounds__(512)
__global__ void encode_mfma_kernel(const unsigned short* __restrict__ Xs,
                                   const unsigned short* __restrict__ Ws,
                                   const float* __restrict__ b_enc,
                                   float* __restrict__ P,   // chunk-local
                                   float* __restrict__ stats, // [16384][2]
                                   int row0) {
    __shared__ unsigned short At[256 * 64];
    __shared__ unsigned short Bt[256 * 64];

    int tid  = threadIdx.x;
    int lane = tid & 63;
    int wid  = tid >> 6;
    int wm   = wid >> 2;
    int wn   = wid & 3;
    int bm   = blockIdx.x * 256;
    int bn   = blockIdx.y * 256;
    int fr   = lane & 15;
    int fk   = (lane >> 4) << 3;

    f32x4 acc[8][4];
    #pragma unroll
    for (int i = 0; i < 8; ++i)
        #pragma unroll
        for (int j = 0; j < 4; ++j) acc[i][j] = (f32x4)0.f;

    int r8 = tid >> 3;          // 0..63
    int b8 = (tid & 7) * 8;     // elem offset, 0..56 step 8

    for (int k0 = 0; k0 < D_IN; k0 += 32) {
        int c = k0 >> 5;
        // stage: linear copies (presplit, pre-swizzled) — conflict-light
        #pragma unroll
        for (int q = 0; q < 4; ++q) {
            int row = q * 64 + r8;
            *(us8*)&At[row * 64 + b8] =
                *(const us8*)&Xs[((size_t)(row0 + bm + row) * 16 + c) * 64 + b8];
            *(us8*)&Bt[row * 64 + b8] =
                *(const us8*)&Ws[((size_t)(bn + row) * 16 + c) * 64 + b8];
        }
        __syncthreads();

        bf16x8 bh[4], bl[4];
        #pragma unroll
        for (int nj = 0; nj < 4; ++nj) {
            bh[nj] = *(const bf16x8*)&Bt[swz(wn * 64 + nj * 16 + fr, fk)];
            bl[nj] = *(const bf16x8*)&Bt[swz(wn * 64 + nj * 16 + fr, 32 + fk)];
        }
        #pragma unroll
        for (int mi = 0; mi < 8; ++mi) {
            bf16x8 ah = *(const bf16x8*)&At[swz(wm * 128 + mi * 16 + fr, fk)];
            bf16x8 al = *(const bf16x8*)&At[swz(wm * 128 + mi * 16 + fr, 32 + fk)];
            #pragma unroll
            for (int nj = 0; nj < 4; ++nj) {
                acc[mi][nj] = __builtin_amdgcn_mfma_f32_16x16x32_bf16(ah, bh[nj], acc[mi][nj], 0, 0, 0);
                acc[mi][nj] = __builtin_amdgcn_mfma_f32_16x16x32_bf16(ah, bl[nj], acc[mi][nj], 0, 0, 0);
                acc[mi][nj] = __builtin_amdgcn_mfma_f32_16x16x32_bf16(al, bh[nj], acc[mi][nj], 0, 0, 0);
            }
        }
        __syncthreads();
    }

    // epilogue: bias add, store P, per-row partial stats (sum, sum2)
    #pragma unroll
    for (int mi = 0; mi < 8; ++mi) {
        int r0 = bm + wm * 128 + mi * 16 + (lane >> 4) * 4;
        #pragma unroll
        for (int reg = 0; reg < 4; ++reg) {
            float s = 0.f, s2 = 0.f;
            #pragma unroll
            for (int nj = 0; nj < 4; ++nj) {
                int col = bn + wn * 64 + nj * 16 + fr;
                float v = acc[mi][nj][reg] + b_enc[col];
                P[(size_t)(r0 + reg) * D_DICT + col] = v;
                s += v; s2 += v * v;
            }
            #pragma unroll
            for (int m = 1; m < 16; m <<= 1) {
                s  += __shfl_xor(s, m);
                s2 += __shfl_xor(s2, m);
            }
            if (fr == 0) {
                atomicAdd(&stats[(size_t)(row0 + r0 + reg) * 2], s);
                atomicAdd(&stats[(size_t)(row0 + r0 + reg) * 2 + 1], s2);
            }
        }
    }
}

// ---------------------------------------------------------------------------
// Kernel 1b (fallback): exact fp32 encode GEMM (np rounding class).
// ---------------------------------------------------------------------------
#define EBK 8
#define ESTR 132

__launch_bounds__(256)
__global__ void encode_gemm_kernel(const float* __restrict__ X,
                                   const float* __restrict__ Wenc,
                                   const float* __restrict__ b_enc,
                                   float* __restrict__ P,
                                   int row0, int nrows) {
    __shared__ float As[EBK][ESTR];
    __shared__ float Bs[EBK][ESTR];
    int tid = threadIdx.x;
    int tx = tid & 15;
    int ty = tid >> 4;
    int bm = blockIdx.x * 128;
    int bn = blockIdx.y * 128;
    int srow = tid >> 1;
    int skq  = (tid & 1) * 4;

    float acc[8][8];
    #pragma unroll
    for (int i = 0; i < 8; ++i)
        #pragma unroll
        for (int j = 0; j < 8; ++j) acc[i][j] = 0.f;

    for (int k0 = 0; k0 < D_IN; k0 += EBK) {
        float4 a4 = make_float4(0.f, 0.f, 0.f, 0.f);
        if (bm + srow < nrows)
            a4 = *(const float4*)&X[(size_t)(row0 + bm + srow) * D_IN + k0 + skq];
        float4 b4 = *(const float4*)&Wenc[(size_t)(bn + srow) * D_IN + k0 + skq];
        As[skq + 0][srow] = a4.x; As[skq + 1][srow] = a4.y;
        As[skq + 2][srow] = a4.z; As[skq + 3][srow] = a4.w;
        Bs[skq + 0][srow] = b4.x; Bs[skq + 1][srow] = b4.y;
        Bs[skq + 2][srow] = b4.z; Bs[skq + 3][srow] = b4.w;
        __syncthreads();
        #pragma unroll
        for (int k = 0; k < EBK; ++k) {
            float4 a0 = *(const float4*)&As[k][ty * 4];
            float4 a1 = *(const float4*)&As[k][64 + ty * 4];
            float4 b0 = *(const float4*)&Bs[k][tx * 4];
            float4 b1 = *(const float4*)&Bs[k][64 + tx * 4];
            float a[8] = {a0.x, a0.y, a0.z, a0.w, a1.x, a1.y, a1.z, a1.w};
            float b[8] = {b0.x, b0.y, b0.z, b0.w, b1.x, b1.y, b1.z, b1.w};
            #pragma unroll
            for (int i = 0; i < 8; ++i)
                #pragma unroll
                for (int j = 0; j < 8; ++j)
                    acc[i][j] = fmaf(a[i], b[j], acc[i][j]);
        }
        __syncthreads();
    }

    float4 bias0 = *(const float4*)&b_enc[bn + tx * 4];
    float4 bias1 = *(const float4*)&b_enc[bn + 64 + tx * 4];
    float bb[8] = {bias0.x, bias0.y, bias0.z, bias0.w,
                   bias1.x, bias1.y, bias1.z, bias1.w};
    #pragma unroll
    for (int i = 0; i < 8; ++i) {
        int r = bm + (i < 4 ? ty * 4 + i : 64 + ty * 4 + (i - 4));
        if (r < nrows) {
            float4 o0, o1;
            o0.x = acc[i][0] + bb[0]; o0.y = acc[i][1] + bb[1];
            o0.z = acc[i][2] + bb[2]; o0.w = acc[i][3] + bb[3];
            o1.x = acc[i][4] + bb[4]; o1.y = acc[i][5] + bb[5];
            o1.z = acc[i][6] + bb[6]; o1.w = acc[i][7] + bb[7];
            *(float4*)&P[(size_t)r * D_DICT + bn + tx * 4] = o0;
            *(float4*)&P[(size_t)r * D_DICT + bn + 64 + tx * 4] = o1;
        }
    }
}

// ---------------------------------------------------------------------------
// Kernel 2 (v5): top-256. If stats != nullptr: single P pass (zero-fill +
// candidate collect using precomputed mu/sigma). Else: two-pass internal
// stats (Tier C). Everything downstream identical to validated v4: radix over
// candidates, margin check, full-radix-from-global fallback, exact band
// recompute in np rounding class (ascending-k fmaf), ties -> lowest index.
// ---------------------------------------------------------------------------
__launch_bounds__(256)
__global__ void topk_band_kernel(const float* __restrict__ P,  // chunk-local
                                 int row0,
                                 const float* __restrict__ x,
                                 const float* __restrict__ Wenc,
                                 const float* __restrict__ b_enc,
                                 const float* __restrict__ stats, // [16384][2] or null
                                 float* __restrict__ hidden) {
    __shared__ float  cand_val[CCAP];      // 8 KiB
    __shared__ int    cand_idx[CCAP];      // 8 KiB
    __shared__ uint32 hist[256];           // 1 KiB
    __shared__ float  redS[4], redS2[4];
    __shared__ float  sh_mu, sh_sig;
    __shared__ uint32 sh_prefix, sh_need;
    __shared__ int    sh_cnt, c_clear, bcnt;
    __shared__ int    bidx_s[BCAP];
    __shared__ float  bval_s[BCAP];

    int lrow = blockIdx.x;
    int grow = row0 + lrow;
    const float* p = P + (size_t)lrow * D_DICT;
    float* hrow = hidden + (size_t)grow * D_DICT;
    int t = threadIdx.x;

    float Tlo;
    if (t == 0) sh_cnt = 0;

    if (stats != nullptr) {
        float S  = stats[(size_t)grow * 2];
        float S2 = stats[(size_t)grow * 2 + 1];
        float mu = S * (1.f / D_DICT);
        float var = S2 * (1.f / D_DICT) - mu * mu;
        Tlo = mu + 1.3f * sqrtf(fmaxf(var, 1e-20f));
        __syncthreads();
        // single pass: zero-fill hidden + collect candidates
        #pragma unroll 2
        for (int c = 0; c < 8; ++c) {
            int e4 = c * 256 + t;
            float4 v4 = ((const float4*)p)[e4];
            *(float4*)&hrow[e4 * 4] = make_float4(0.f, 0.f, 0.f, 0.f);
            float vv[4] = {v4.x, v4.y, v4.z, v4.w};
            #pragma unroll
            for (int j = 0; j < 4; ++j) {
                if (vv[j] > Tlo) {
                    int slot = atomicAdd((uint32*)&sh_cnt, 1u);
                    if (slot < CCAP) { cand_val[slot] = vv[j]; cand_idx[slot] = e4 * 4 + j; }
                }
            }
        }
    } else {
        // Tier C path: pass 1 stats + zero-fill
        float s = 0.f, s2 = 0.f;
        #pragma unroll 2
        for (int c = 0; c < 8; ++c) {
            int e4 = c * 256 + t;
            float4 v4 = ((const float4*)p)[e4];
            s  += v4.x + v4.y + v4.z + v4.w;
            s2 += v4.x*v4.x + v4.y*v4.y + v4.z*v4.z + v4.w*v4.w;
            *(float4*)&hrow[e4 * 4] = make_float4(0.f, 0.f, 0.f, 0.f);
        }
        #pragma unroll
        for (int off = 32; off; off >>= 1) {
            s  += __shfl_down(s, off);
            s2 += __shfl_down(s2, off);
        }
        if ((t & 63) == 0) { redS[t >> 6] = s; redS2[t >> 6] = s2; }
        __syncthreads();
        if (t == 0) {
            float S  = redS[0] + redS[1] + redS[2] + redS[3];
            float S2 = redS2[0] + redS2[1] + redS2[2] + redS2[3];
            float mu = S * (1.f / D_DICT);
            float var = S2 * (1.f / D_DICT) - mu * mu;
            sh_mu = mu;
            sh_sig = sqrtf(fmaxf(var, 1e-20f));
        }
        __syncthreads();
        Tlo = sh_mu + 1.3f * sh_sig;
        // pass 2: collect
        #pragma unroll 2
        for (int c = 0; c < 8; ++c) {
            int e4 = c * 256 + t;
            float4 v4 = ((const float4*)p)[e4];
            float vv[4] = {v4.x, v4.y, v4.z, v4.w};
            #pragma unroll
            for (int j = 0; j < 4; ++j) {
                if (vv[j] > Tlo) {
                    int slot = atomicAdd((uint32*)&sh_cnt, 1u);
                    if (slot < CCAP) { cand_val[slot] = vv[j]; cand_idx[slot] = e4 * 4 + j; }
                }
            }
        }
    }
    __syncthreads();
    int n = sh_cnt;
    bool found = (n >= TOPK && n <= CCAP);

    // radix select (candidates; full-global fallback if pruning unsafe)
    float vT0 = 0.f;
    for (int rtry = 0; rtry < 2; ++rtry) {
        uint32 prefix = 0, need = TOPK;
        for (int pass = 0; pass < 4; ++pass) {
            int shift = 24 - 8 * pass;
            hist[t] = 0;
            __syncthreads();
            uint32 mask_hi = pass ? (0xFFFFFFFFu << (shift + 8)) : 0u;
            if (found) {
                for (int e = t; e < n; e += 256) {
                    uint32 u = okey(cand_val[e]);
                    if ((u & mask_hi) == prefix)
                        atomicAdd(&hist[(u >> shift) & 255u], 1u);
                }
            } else {
                for (int e = t; e < D_DICT; e += 256) {
                    uint32 u = okey(p[e]);
                    if ((u & mask_hi) == prefix)
                        atomicAdd(&hist[(u >> shift) & 255u], 1u);
                }
            }
            __syncthreads();
            if (t == 0) {
                uint32 cum = 0;
                int d = 255;
                for (; d > 0; --d) {
                    uint32 h = hist[d];
                    if (cum + h >= need) break;
                    cum += h;
                }
                sh_prefix = prefix | ((uint32)d << shift);
                sh_need = need - cum;
            }
            __syncthreads();
            prefix = sh_prefix;
            need = sh_need;
            __syncthreads();
        }
        uint32 tb = (prefix & 0x80000000u) ? (prefix & 0x7FFFFFFFu) : ~prefix;
        vT0 = __uint_as_float(tb);
        if (!found) break;                       // fallback result is final
        if (vT0 - BAND - 1e-3f > Tlo) break;     // pruning provably safe
        found = false;                           // margin violated -> full radix
        __syncthreads();
    }

    // classify: clear winners write approx value; band entries -> exact list
    if (t == 0) { c_clear = 0; bcnt = 0; }
    __syncthreads();
    if (found) {
        for (int e = t; e < n; e += 256) {
            float v = cand_val[e];
            int i = cand_idx[e];
            if (v > vT0 + BAND) {
                hrow[i] = fmaxf(v, 0.f);
                atomicAdd((uint32*)&c_clear, 1u);
            } else if (v >= vT0 - BAND) {
                int slot = atomicAdd((uint32*)&bcnt, 1u);
                if (slot < BCAP) bidx_s[slot] = i;
            }
        }
    } else {
        for (int e = t; e < D_DICT; e += 256) {
            float v = p[e];
            if (v > vT0 + BAND) {
                hrow[e] = fmaxf(v, 0.f);
                atomicAdd((uint32*)&c_clear, 1u);
            } else if (v >= vT0 - BAND) {
                int slot = atomicAdd((uint32*)&bcnt, 1u);
                if (slot < BCAP) bidx_s[slot] = e;
            }
        }
    }
    __syncthreads();

    // exact recompute of band entries (np rounding class: ascending-k fmaf)
    int nb = bcnt < BCAP ? bcnt : BCAP;
    if (t < nb) {
        const float* xr = x + (size_t)grow * D_IN;
        const float* wr = Wenc + (size_t)bidx_s[t] * D_IN;
        float acc = 0.f;
        #pragma unroll 8
        for (int k = 0; k < D_IN; ++k)   // ascending k — do not reorder
            acc = fmaf(xr[k], wr[k], acc);
        bval_s[t] = acc + b_enc[bidx_s[t]];
    }
    __syncthreads();
    if (t == 0) {
        int take = TOPK - c_clear;
        for (int rr = 0; rr < take; ++rr) {
            int best = -1; float bv = 0.f; int bi = 0;
            for (int e = 0; e < nb; ++e) {
                int idx = bidx_s[e];
                if (idx < 0) continue;
                float v = bval_s[e];
                if (best < 0 || v > bv || (v == bv && idx < bi)) {
                    best = e; bv = v; bi = idx;
                }
            }
            if (best < 0) break;
            bidx_s[best] = -1;
            hrow[bi] = fmaxf(bv, 0.f);
        }
    }
}

// ---------------------------------------------------------------------------
// Kernel 3: dense bf16 MFMA decode (validated rounds 5-9).
// ---------------------------------------------------------------------------
__launch_bounds__(512)
__global__ void mfma_decode_kernel(const float* __restrict__ hidden,
                                   const unsigned short* __restrict__ Wb,
                                   const float* __restrict__ b_dec,
                                   float* __restrict__ recon) {
    __shared__ unsigned short At[256 * 64];
    __shared__ unsigned short Bt[256 * 64];

    int tid  = threadIdx.x;
    int lane = tid & 63;
    int wid  = tid >> 6;
    int wm   = wid >> 2;
    int wn   = wid & 3;

    int bid = blockIdx.x;
    int bn  = (bid & 1) * 256;
    int bm  = (bid >> 1) * 256;

    f32x4 acc[8][4];
    #pragma unroll
    for (int i = 0; i < 8; ++i)
        #pragma unroll
        for (int j = 0; j < 4; ++j) acc[i][j] = (f32x4)0.f;

    for (int k0 = 0; k0 < D_DICT; k0 += 64) {
        #pragma unroll
        for (int i = 0; i < 8; ++i) {
            int idx = i * 512 + tid;
            int row = idx >> 4;
            int kq  = (idx & 15) * 4;
            float4 h4 = *(const float4*)&hidden[(size_t)(bm + row) * D_DICT + k0 + kq];
            us4 o;
            o.x = f2bf_rne(h4.x); o.y = f2bf_rne(h4.y);
            o.z = f2bf_rne(h4.z); o.w = f2bf_rne(h4.w);
            *(us4*)&At[swz(row, kq)] = o;
        }
        #pragma unroll
        for (int i = 0; i < 4; ++i) {
            int idx = i * 512 + tid;
            int row = idx >> 3;
            int kq8 = (idx & 7) * 8;
            us8 w8 = *(const us8*)&Wb[(size_t)(bn + row) * D_DICT + k0 + kq8];
            *(us8*)&Bt[swz(row, kq8)] = w8;
        }
        __syncthreads();

        #pragma unroll
        for (int ks = 0; ks < 2; ++ks) {
            int kb = ks * 32 + (lane >> 4) * 8;
            bf16x8 av[8], bv[4];
            #pragma unroll
            for (int mi = 0; mi < 8; ++mi)
                av[mi] = *(const bf16x8*)&At[swz(wm * 128 + mi * 16 + (lane & 15), kb)];
            #pragma unroll
            for (int nj = 0; nj < 4; ++nj)
                bv[nj] = *(const bf16x8*)&Bt[swz(wn * 64 + nj * 16 + (lane & 15), kb)];
            #pragma unroll
            for (int mi = 0; mi < 8; ++mi)
                #pragma unroll
                for (int nj = 0; nj < 4; ++nj)
                    acc[mi][nj] = __builtin_amdgcn_mfma_f32_16x16x32_bf16(
                        av[mi], bv[nj], acc[mi][nj], 0, 0, 0);
        }
        __syncthreads();
    }

    #pragma unroll
    for (int mi = 0; mi < 8; ++mi) {
        int r0 = bm + wm * 128 + mi * 16 + (lane >> 4) * 4;
        #pragma unroll
        for (int nj = 0; nj < 4; ++nj) {
            int col = bn + wn * 64 + nj * 16 + (lane & 15);
            float bd = b_dec[col];
            #pragma unroll
            for (int reg = 0; reg < 4; ++reg)
                recon[(size_t)(r0 + reg) * D_IN + col] = acc[mi][nj][reg] + bd;
        }
    }
}

// ---------------------------------------------------------------------------
// Kernel 3b: exact gather decode (tiny-ws fallback)
// ---------------------------------------------------------------------------
__launch_bounds__(256)
__global__ void decode_direct_kernel(const float* __restrict__ hidden,
                                     const float* __restrict__ W_dec,
                                     const float* __restrict__ b_dec,
                                     float* __restrict__ recon) {
    __shared__ float  sv[TOPK];
    __shared__ int    sidx[TOPK];
    __shared__ int    offs[257];
    int row = blockIdx.x;
    int t = threadIdx.x;
    const float* hrow = hidden + (size_t)row * D_DICT;

    int base = t * 32;
    int c = 0;
    for (int j = 0; j < 32; ++j) c += (hrow[base + j] > 0.f) ? 1 : 0;
    offs[t + 1] = c;
    __syncthreads();
    if (t == 0) {
        offs[0] = 0;
        for (int i = 0; i < 256; ++i) offs[i + 1] += offs[i];
    }
    __syncthreads();
    int o = offs[t];
    for (int j = 0; j < 32; ++j) {
        float v = hrow[base + j];
        if (v > 0.f) { sv[o] = v; sidx[o] = base + j; ++o; }
    }
    __syncthreads();
    int total = offs[256];

    int d0 = 2 * t;
    float acc0 = b_dec[d0];
    float acc1 = b_dec[d0 + 1];
    for (int k = 0; k < total; ++k) {
        float v = sv[k];
        int idx = sidx[k];
        acc0 = fmaf(v, W_dec[(size_t)d0 * D_DICT + idx], acc0);
        acc1 = fmaf(v, W_dec[(size_t)(d0 + 1) * D_DICT + idx], acc1);
    }
    *(float2*)&recon[(size_t)row * D_IN + d0] = make_float2(acc0, acc1);
}

// ---------------------------------------------------------------------------
extern "C" void kernel_launch(void* const* d_in, const int* in_sizes, int n_in,
                              void* d_out, int out_size, void* d_ws, size_t ws_size,
                              hipStream_t stream) {
    const float* x     = (const float*)d_in[0];
    const float* W_enc = (const float*)d_in[1];
    const float* b_enc = (const float*)d_in[2];
    const float* W_dec = (const float*)d_in[3];
    const float* b_dec = (const float*)d_in[4];

    float* out    = (float*)d_out;
    float* recon  = out;                          // 16384*512 fp32
    float* hidden = out + (size_t)N_ROWS * D_IN;  // 16384*8192 fp32

    const size_t STATS_BYTES = (size_t)N_ROWS * 2 * sizeof(float);              // 128 KiB
    const size_t WB_BYTES    = (size_t)D_IN * D_DICT * sizeof(unsigned short);  // 8 MiB
    const size_t WS_BYTES    = (size_t)D_DICT * 16 * 64 * sizeof(unsigned short); // 16 MiB
    const size_t XS_BYTES    = (size_t)N_ROWS * 16 * 64 * sizeof(unsigned short); // 32 MiB
    const size_t ROW_BYTES   = (size_t)D_DICT * sizeof(float);                  // 32 KiB
    const size_t FIXED       = STATS_BYTES + WB_BYTES + WS_BYTES + XS_BYTES;    // ~56 MiB

    char* ws = (char*)d_ws;

    if (ws_size >= FIXED + 256 * ROW_BYTES) {
        // Tier B: presplit MFMA encode (+stats) + single-pass topk + MFMA decode
        float*          statsb = (float*)ws;
        unsigned short* Wb     = (unsigned short*)(ws + STATS_BYTES);
        unsigned short* Wsp    = (unsigned short*)(ws + STATS_BYTES + WB_BYTES);
        unsigned short* Xsp    = (unsigned short*)(ws + STATS_BYTES + WB_BYTES + WS_BYTES);
        float*          pre    = (float*)(ws + FIXED);
        size_t avail = ws_size - FIXED;

        long long cl = (long long)(avail / ROW_BYTES);
        int chunk = (cl > N_ROWS) ? N_ROWS : (int)cl;
        chunk &= ~255;

        hipMemsetAsync(statsb, 0, STATS_BYTES, stream);
        cast_wdec_kernel<<<(D_IN * D_DICT) / 1024, 256, 0, stream>>>(W_dec, Wb);
        split_hilo_kernel<<<(D_DICT * 16) / 256, 256, 0, stream>>>(W_enc, Wsp);
        split_hilo_kernel<<<(N_ROWS * 16) / 256, 256, 0, stream>>>(x, Xsp);

        for (int r0 = 0; r0 < N_ROWS; r0 += chunk) {
            int nr = (N_ROWS - r0 < chunk) ? (N_ROWS - r0) : chunk;
            encode_mfma_kernel<<<dim3(nr / 256, D_DICT / 256), 512, 0, stream>>>(
                Xsp, Wsp, b_enc, pre, statsb, r0);
            topk_band_kernel<<<nr, 256, 0, stream>>>(pre, r0, x, W_enc, b_enc, statsb, hidden);
        }

        mfma_decode_kernel<<<(N_ROWS / 256) * 2, 512, 0, stream>>>(hidden, Wb, b_dec, recon);
    } else {
        // Tier C: exact fp32 encode + two-pass topk + gather decode (tiny ws)
        float* pre = (float*)ws;
        long long cl = (long long)(ws_size / ROW_BYTES);
        int chunk;
        if (cl >= 128) { chunk = (cl > 2048) ? 2048 : (int)cl; chunk &= ~127; }
        else chunk = (cl < 1) ? 1 : (int)cl;

        for (int r0 = 0; r0 < N_ROWS; r0 += chunk) {
            int nr = (N_ROWS - r0 < chunk) ? (N_ROWS - r0) : chunk;
            dim3 grid((nr + 127) / 128, D_DICT / 128);
            encode_gemm_kernel<<<grid, 256, 0, stream>>>(x, W_enc, b_enc, pre, r0, nr);
            topk_band_kernel<<<nr, 256, 0, stream>>>(pre, r0, x, W_enc, b_enc, nullptr, hidden);
        }
        decode_direct_kernel<<<N_ROWS, 256, 0, stream>>>(hidden, W_dec, b_dec, recon);
    }
}